// Round 4
// baseline (221.451 us; speedup 1.0000x reference)
//
#include <hip/hip_runtime.h>

#define BOND   64
#define SITES  256
#define HALF   128
#define NBATCH 128
#define OUTD   10
#define SITE_FLOATS 8192                 // 64*64*2 floats per packed site

// d_ws float layout:
//   PL : [0 .. 1048576)          left-packed  [128 steps][f][q][r] float4 = c_f[4q+u][r]
//   PR : [1048576 .. 2097152)    right-packed [128 steps][f][q][l] float4 = c_f[l][4q+u], step k = site 255-k
//   vecs: [2097152 .. 2113536)   [2][128][64] propagated end vectors
#define PR_OFF   (HALF * SITE_FLOATS)
#define VEC_OFF  (2 * HALF * SITE_FLOATS)
#define LPITCH   132                     // pack-kernel LDS transpose pitch

typedef const float __attribute__((address_space(1)))* gas1_fp;
typedef float __attribute__((address_space(3)))* gas3_fp;

__device__ __forceinline__ void gload_lds16(const float* g, float* l) {
  // wave-uniform LDS base + lane*16B; per-lane global address
  __builtin_amdgcn_global_load_lds((gas1_fp)g, (gas3_fp)l, 16, 0, 0);
}

// ---------------------------------------------------------------------------
// Pack: one block per site. cores[s][l][r][f] -> per-side chain-read-optimal
// layout, so the chain kernel's ds_read_b128 is lane-contiguous (zero-conflict):
//   left  (s < 128):  PL[s][f][q][r]      = {c_f[4q+u][r]}  u=0..3
//   right (s >= 128): PR[255-s][f][q][l]  = {c_f[l][4q+u]}  u=0..3
// ---------------------------------------------------------------------------
__global__ void __launch_bounds__(256)
mps_pack_kernel(const float* __restrict__ cores, float* __restrict__ P) {
  __shared__ __align__(16) float ld[64 * LPITCH];
  const int s = (int)blockIdx.x;
  const int t = (int)threadIdx.x;
  const float4* src = (const float4*)(cores + (size_t)s * SITE_FLOATS);
  #pragma unroll
  for (int k = 0; k < 8; ++k) {
    const int m = t + 256 * k;            // float4 index in [0,2048)
    const int row = m >> 5;               // l
    const int c4  = m & 31;
    *(float4*)&ld[row * LPITCH + c4 * 4] = src[m];
  }
  __syncthreads();
  const bool right = s >= HALF;
  const int step = right ? (SITES - 1 - s) : s;
  float4* out = (float4*)(P + (right ? PR_OFF : 0) + (size_t)step * SITE_FLOATS);
  #pragma unroll
  for (int k = 0; k < 8; ++k) {
    const int m2 = t + 256 * k;           // out float4 index = (f*16+q)*64 + j
    const int j  = m2 & 63;
    const int fq = m2 >> 6;
    const int f  = fq >> 4;
    const int q  = fq & 15;
    float4 v;
    if (!right) {                         // {c[4q+u][j][f]}
      v.x = ld[(4 * q + 0) * LPITCH + 2 * j + f];
      v.y = ld[(4 * q + 1) * LPITCH + 2 * j + f];
      v.z = ld[(4 * q + 2) * LPITCH + 2 * j + f];
      v.w = ld[(4 * q + 3) * LPITCH + 2 * j + f];
    } else {                              // {c[j][4q+u][f]}
      v.x = ld[j * LPITCH + 2 * (4 * q + 0) + f];
      v.y = ld[j * LPITCH + 2 * (4 * q + 1) + f];
      v.z = ld[j * LPITCH + 2 * (4 * q + 2) + f];
      v.w = ld[j * LPITCH + 2 * (4 * q + 3) + f];
    }
    out[m2] = v;
  }
}

// ---------------------------------------------------------------------------
// Chain: 256 blocks x 64 threads. ONE wave per chain, no split-K, no barriers.
// LDS double-buffered site staging via global_load_lds (32 x 16B-wide loads),
// v-vector lives in wave-private LDS, read back as same-address b128 broadcasts
// (DS in-order within a wave => no sync needed).
//   left : v_new[r=lane] = v[r] + sum_f x_f * sum_l v[l] * c_f[l][r]
//   right: w_new[l=lane] = w[l] + sum_f x_f * sum_r c_f[l][r] * w[r]
// ---------------------------------------------------------------------------
__global__ void __launch_bounds__(64, 1)
mps_chain_kernel(const float* __restrict__ input,   // [128][256][2]
                 const float* __restrict__ P,       // packed cores (in ws)
                 const float* __restrict__ lvec,
                 const float* __restrict__ rvec,
                 float* __restrict__ vout) {        // ws + VEC_OFF
  __shared__ __align__(16) float buf[2][SITE_FLOATS];   // 2 x 32 KB
  __shared__ __align__(16) float xsh[HALF * 2];
  __shared__ __align__(16) float vsh[BOND];

  const int lane = (int)threadIdx.x;
  const int side = (int)blockIdx.x & 1;
  const int b    = (int)blockIdx.x >> 1;

  ((float4*)xsh)[lane] =
      ((const float4*)(input + (size_t)b * SITES * 2 + side * HALF * 2))[lane];
  float vcur = side ? rvec[lane] : lvec[lane];
  vsh[lane] = vcur;

  const float* base = P + (side ? PR_OFF : 0);

  // prologue: stage step 0 into buf[0]
  #pragma unroll
  for (int c = 0; c < 32; ++c)
    gload_lds16(base + c * 256 + lane * 4, &buf[0][c * 256]);

  for (int i = 0; i < HALF; ++i) {
    // prefetch next step into the alternate buffer (last iter: harmless refetch)
    const float* g = base + (size_t)((i + 1 < HALF) ? i + 1 : i) * SITE_FLOATS;
    float* nb = buf[(i & 1) ^ 1];
    #pragma unroll
    for (int c = 0; c < 32; ++c)
      gload_lds16(g + c * 256 + lane * 4, &nb[c * 256]);
    // wait for current buffer's 32 loads; the 32 just issued stay in flight
    asm volatile("s_waitcnt vmcnt(32)" ::: "memory");

    const float* B = buf[i & 1];
    float acc0 = 0.f, acc1 = 0.f, acc2 = 0.f, acc3 = 0.f;
    #pragma unroll
    for (int q = 0; q < 16; ++q) {
      const float4 vq = ((const float4*)vsh)[q];                    // broadcast
      const float4 m0 = ((const float4*)(B + q * 256))[lane];       // f = 0
      const float4 m1 = ((const float4*)(B + 4096 + q * 256))[lane];// f = 1
      acc0 = __builtin_fmaf(vq.x, m0.x, __builtin_fmaf(vq.y, m0.y, acc0));
      acc2 = __builtin_fmaf(vq.z, m0.z, __builtin_fmaf(vq.w, m0.w, acc2));
      acc1 = __builtin_fmaf(vq.x, m1.x, __builtin_fmaf(vq.y, m1.y, acc1));
      acc3 = __builtin_fmaf(vq.z, m1.z, __builtin_fmaf(vq.w, m1.w, acc3));
    }
    const int xi = side ? (HALF - 1 - i) : i;
    const float2 xx = ((const float2*)xsh)[xi];
    vcur = __builtin_fmaf(xx.x, acc0 + acc2,
           __builtin_fmaf(xx.y, acc1 + acc3, vcur));
    vsh[lane] = vcur;   // single wave: DS in-order, next step's reads see this
  }

  vout[((size_t)side * NBATCH + b) * BOND + lane] = vcur;
}

// ---------------------------------------------------------------------------
// Combine: 128 blocks x 640 threads (10 waves, wave = output o).
// logits[b][o] = sum_{m,r} vL[b][m] * oc[o][m][r] * vR[b][r]
// vL[m] via wave-uniform scalar loads; oc reads fully coalesced; shuffle-reduce.
// ---------------------------------------------------------------------------
__global__ void __launch_bounds__(640)
mps_combine_kernel(const float* __restrict__ oc,    // [10][64][64]
                   const float* __restrict__ vecs,  // ws + VEC_OFF
                   float* __restrict__ out) {       // [128][10]
  const int t = (int)threadIdx.x;
  const int o = t >> 6;           // 0..9
  const int r = t & 63;
  const int b = (int)blockIdx.x;
  const float* vl = vecs + (size_t)b * BOND;
  const float vr = vecs[(size_t)NBATCH * BOND + b * BOND + r];
  float acc = 0.f;
  #pragma unroll
  for (int m = 0; m < BOND; ++m)
    acc = __builtin_fmaf(vl[m], oc[(o * BOND + m) * BOND + r], acc);
  acc *= vr;
  #pragma unroll
  for (int off = 32; off > 0; off >>= 1)
    acc += __shfl_xor(acc, off, 64);
  if (r == 0) out[b * OUTD + o] = acc;
}

extern "C" void kernel_launch(void* const* d_in, const int* in_sizes, int n_in,
                              void* d_out, int out_size, void* d_ws, size_t ws_size,
                              hipStream_t stream) {
  const float* input = (const float*)d_in[0];   // [128][256][2]
  const float* cores = (const float*)d_in[1];   // [256][64][64][2]
  const float* oc    = (const float*)d_in[2];   // [10][64][64]
  const float* lvec  = (const float*)d_in[3];   // [64]
  const float* rvec  = (const float*)d_in[4];   // [64]
  float* ws  = (float*)d_ws;
  float* out = (float*)d_out;                   // [128][10]

  hipLaunchKernelGGL(mps_pack_kernel, dim3(SITES), dim3(256), 0, stream,
                     cores, ws);
  hipLaunchKernelGGL(mps_chain_kernel, dim3(2 * NBATCH), dim3(64), 0, stream,
                     input, ws, lvec, rvec, ws + VEC_OFF);
  hipLaunchKernelGGL(mps_combine_kernel, dim3(NBATCH), dim3(640), 0, stream,
                     oc, ws + VEC_OFF, out);
}

// Round 5
// 202.928 us; speedup vs baseline: 1.0913x; 1.0913x over previous
//
#include <hip/hip_runtime.h>

#define BOND   64
#define SITES  256
#define HALF   128
#define NBATCH 128
#define OUTD   10
#define SITE_FLOATS 8192                 // 64*64*2 floats per packed site

// d_ws float layout:
//   PL : [0 .. 1048576)          left-packed  [128 steps][f][q][r] float4 = c_f[4q+u][r]
//   PR : [1048576 .. 2097152)    right-packed [128 steps][f][q][l] float4 = c_f[l][4q+u], step k = site 255-k
//   vecs: [2097152 .. 2113536)   [2][128][64] propagated end vectors
#define PR_OFF   (HALF * SITE_FLOATS)
#define VEC_OFF  (2 * HALF * SITE_FLOATS)
#define LPITCH   132                     // pack-kernel LDS transpose pitch

typedef const float __attribute__((address_space(1)))* gas1_fp;
typedef float __attribute__((address_space(3)))* gas3_fp;

__device__ __forceinline__ void gload_lds16(const float* g, float* l) {
  // wave-uniform LDS base + lane*16B; per-lane global address
  __builtin_amdgcn_global_load_lds((gas1_fp)g, (gas3_fp)l, 16, 0, 0);
}

// ---------------------------------------------------------------------------
// Pack: one block per site. cores[s][l][r][f] -> per-side chain-read-optimal
// layout (lane-contiguous float4, zero-conflict ds_read_b128 in the chain):
//   left  (s < 128):  PL[s][f][q][r]      = {c_f[4q+u][r]}  u=0..3
//   right (s >= 128): PR[255-s][f][q][l]  = {c_f[l][4q+u]}  u=0..3
// ---------------------------------------------------------------------------
__global__ void __launch_bounds__(256)
mps_pack_kernel(const float* __restrict__ cores, float* __restrict__ P) {
  __shared__ __align__(16) float ld[64 * LPITCH];
  const int s = (int)blockIdx.x;
  const int t = (int)threadIdx.x;
  const float4* src = (const float4*)(cores + (size_t)s * SITE_FLOATS);
  #pragma unroll
  for (int k = 0; k < 8; ++k) {
    const int m = t + 256 * k;            // float4 index in [0,2048)
    const int row = m >> 5;               // l
    const int c4  = m & 31;
    *(float4*)&ld[row * LPITCH + c4 * 4] = src[m];
  }
  __syncthreads();
  const bool right = s >= HALF;
  const int step = right ? (SITES - 1 - s) : s;
  float4* out = (float4*)(P + (right ? PR_OFF : 0) + (size_t)step * SITE_FLOATS);
  #pragma unroll
  for (int k = 0; k < 8; ++k) {
    const int m2 = t + 256 * k;           // out float4 index = (f*16+q)*64 + j
    const int j  = m2 & 63;
    const int fq = m2 >> 6;
    const int f  = fq >> 4;
    const int q  = fq & 15;
    float4 v;
    if (!right) {                         // {c_f[4q+u][j]}
      v.x = ld[(4 * q + 0) * LPITCH + 2 * j + f];
      v.y = ld[(4 * q + 1) * LPITCH + 2 * j + f];
      v.z = ld[(4 * q + 2) * LPITCH + 2 * j + f];
      v.w = ld[(4 * q + 3) * LPITCH + 2 * j + f];
    } else {                              // {c_f[j][4q+u]}
      v.x = ld[j * LPITCH + 2 * (4 * q + 0) + f];
      v.y = ld[j * LPITCH + 2 * (4 * q + 1) + f];
      v.z = ld[j * LPITCH + 2 * (4 * q + 2) + f];
      v.w = ld[j * LPITCH + 2 * (4 * q + 3) + f];
    }
    out[m2] = v;
  }
}

// ---------------------------------------------------------------------------
// Chain: 256 blocks x 64 threads. ONE wave per chain, no barriers, and NO
// memory op on the serial critical path: v is broadcast via v_readlane into
// wave-uniform SGPRs (pure VALU, no waitcnt). Matrix data double-buffered in
// LDS via global_load_lds (zero-VGPR prefetch), consumed as conflict-free
// lane-contiguous ds_read_b128 that the compiler can pipeline freely.
//   left : v_new[r=lane] = v[r] + sum_f x_f * sum_l v[l] * c_f[l][r]
//   right: w_new[l=lane] = w[l] + sum_f x_f * sum_r c_f[l][r] * w[r]
// ---------------------------------------------------------------------------
__global__ void __launch_bounds__(64, 1)
mps_chain_kernel(const float* __restrict__ input,   // [128][256][2]
                 const float* __restrict__ P,       // packed cores (in ws)
                 const float* __restrict__ lvec,
                 const float* __restrict__ rvec,
                 float* __restrict__ vout) {        // ws + VEC_OFF
  __shared__ __align__(16) float buf[2][SITE_FLOATS];   // 2 x 32 KB
  __shared__ __align__(16) float xsh[HALF * 2];

  const int lane = (int)threadIdx.x;
  const int side = (int)blockIdx.x & 1;
  const int b    = (int)blockIdx.x >> 1;

  ((float4*)xsh)[lane] =
      ((const float4*)(input + (size_t)b * SITES * 2 + side * HALF * 2))[lane];
  float vcur = side ? rvec[lane] : lvec[lane];

  const float* base = P + (side ? PR_OFF : 0);

  // prologue: stage step 0 into buf[0]
  #pragma unroll
  for (int c = 0; c < 32; ++c)
    gload_lds16(base + c * 256 + lane * 4, &buf[0][c * 256]);

  for (int i = 0; i < HALF; ++i) {
    // prefetch next step into the alternate buffer (last iter: harmless refetch)
    const float* g = base + (size_t)((i + 1 < HALF) ? i + 1 : i) * SITE_FLOATS;
    float* nb = buf[(i & 1) ^ 1];
    #pragma unroll
    for (int c = 0; c < 32; ++c)
      gload_lds16(g + c * 256 + lane * 4, &nb[c * 256]);

    // broadcast v into wave-uniform SGPRs — VALU only, nothing to wait on
    float sv[BOND];
    #pragma unroll
    for (int l = 0; l < BOND; ++l)
      sv[l] = __int_as_float(__builtin_amdgcn_readlane(__float_as_int(vcur), l));

    // x for this step (own earlier ds_write, single wave => in-order, visible)
    const int xi = side ? (HALF - 1 - i) : i;
    const float2 xx = ((const float2*)xsh)[xi];

    // wait for current buffer's 32 loads; the 32 just issued stay in flight
    asm volatile("s_waitcnt vmcnt(32)" ::: "memory");

    const float* B = buf[i & 1];
    float a0 = 0.f, a1 = 0.f, c0 = 0.f, c1 = 0.f;
    #pragma unroll
    for (int q = 0; q < 16; ++q) {
      const float4 m0 = ((const float4*)(B + q * 256))[lane];        // f = 0
      const float4 m1 = ((const float4*)(B + 4096 + q * 256))[lane]; // f = 1
      a0 = __builtin_fmaf(sv[4 * q + 0], m0.x, a0);
      a1 = __builtin_fmaf(sv[4 * q + 1], m0.y, a1);
      a0 = __builtin_fmaf(sv[4 * q + 2], m0.z, a0);
      a1 = __builtin_fmaf(sv[4 * q + 3], m0.w, a1);
      c0 = __builtin_fmaf(sv[4 * q + 0], m1.x, c0);
      c1 = __builtin_fmaf(sv[4 * q + 1], m1.y, c1);
      c0 = __builtin_fmaf(sv[4 * q + 2], m1.z, c0);
      c1 = __builtin_fmaf(sv[4 * q + 3], m1.w, c1);
    }
    vcur = __builtin_fmaf(xx.x, a0 + a1, __builtin_fmaf(xx.y, c0 + c1, vcur));
  }

  vout[((size_t)side * NBATCH + b) * BOND + lane] = vcur;
}

// ---------------------------------------------------------------------------
// Combine: 128 blocks x 640 threads (10 waves, wave = output o).
// logits[b][o] = sum_{m,r} vL[b][m] * oc[o][m][r] * vR[b][r]
// ---------------------------------------------------------------------------
__global__ void __launch_bounds__(640)
mps_combine_kernel(const float* __restrict__ oc,    // [10][64][64]
                   const float* __restrict__ vecs,  // ws + VEC_OFF
                   float* __restrict__ out) {       // [128][10]
  const int t = (int)threadIdx.x;
  const int o = t >> 6;           // 0..9
  const int r = t & 63;
  const int b = (int)blockIdx.x;
  const float* vl = vecs + (size_t)b * BOND;
  const float vr = vecs[(size_t)NBATCH * BOND + b * BOND + r];
  float acc = 0.f;
  #pragma unroll
  for (int m = 0; m < BOND; ++m)
    acc = __builtin_fmaf(vl[m], oc[(o * BOND + m) * BOND + r], acc);
  acc *= vr;
  #pragma unroll
  for (int off = 32; off > 0; off >>= 1)
    acc += __shfl_xor(acc, off, 64);
  if (r == 0) out[b * OUTD + o] = acc;
}

extern "C" void kernel_launch(void* const* d_in, const int* in_sizes, int n_in,
                              void* d_out, int out_size, void* d_ws, size_t ws_size,
                              hipStream_t stream) {
  const float* input = (const float*)d_in[0];   // [128][256][2]
  const float* cores = (const float*)d_in[1];   // [256][64][64][2]
  const float* oc    = (const float*)d_in[2];   // [10][64][64]
  const float* lvec  = (const float*)d_in[3];   // [64]
  const float* rvec  = (const float*)d_in[4];   // [64]
  float* ws  = (float*)d_ws;
  float* out = (float*)d_out;                   // [128][10]

  hipLaunchKernelGGL(mps_pack_kernel, dim3(SITES), dim3(256), 0, stream,
                     cores, ws);
  hipLaunchKernelGGL(mps_chain_kernel, dim3(2 * NBATCH), dim3(64), 0, stream,
                     input, ws, lvec, rvec, ws + VEC_OFF);
  hipLaunchKernelGGL(mps_combine_kernel, dim3(NBATCH), dim3(640), 0, stream,
                     oc, ws + VEC_OFF, out);
}

// Round 6
// 170.878 us; speedup vs baseline: 1.2960x; 1.1876x over previous
//
#include <hip/hip_runtime.h>

#define BOND   64
#define SITES  256
#define HALF   128
#define NBATCH 128
#define OUTD   10
#define SITE_FLOATS 8192                 // 64*64*2 floats per packed site

// d_ws float layout:
//   PL : [0 .. 1048576)          left-packed  [128 steps][f][q][r] float4 = c_f[4q+u][r]
//   PR : [1048576 .. 2097152)    right-packed [128 steps][f][q][l], step k = site 255-k
//   vecs: [2097152 .. 2113536)   [2][128][64] propagated end vectors
//   cnt : [2113536 ..)           128 ints, per-batch completion counters
#define PR_OFF   (HALF * SITE_FLOATS)
#define VEC_OFF  (2 * HALF * SITE_FLOATS)
#define CNT_OFF  (VEC_OFF + 2 * NBATCH * BOND)
#define LPITCH   132                     // pack-kernel LDS transpose pitch

typedef const float __attribute__((address_space(1)))* gas1_fp;
typedef float __attribute__((address_space(3)))* gas3_fp;

__device__ __forceinline__ void gload_lds16(const float* g, float* l) {
  __builtin_amdgcn_global_load_lds((gas1_fp)g, (gas3_fp)l, 16, 0, 0);
}

// ---------------------------------------------------------------------------
// Pack: one block per site (same transform as R5, verified correct) + zero the
// per-batch counters used by the fused combine in the chain kernel.
// ---------------------------------------------------------------------------
__global__ void __launch_bounds__(256)
mps_pack_kernel(const float* __restrict__ cores, float* __restrict__ P,
                int* __restrict__ cnt) {
  __shared__ __align__(16) float ld[64 * LPITCH];
  const int s = (int)blockIdx.x;
  const int t = (int)threadIdx.x;
  if (s == 0 && t < NBATCH) cnt[t] = 0;
  const float4* src = (const float4*)(cores + (size_t)s * SITE_FLOATS);
  #pragma unroll
  for (int k = 0; k < 8; ++k) {
    const int m = t + 256 * k;
    const int row = m >> 5;
    const int c4  = m & 31;
    *(float4*)&ld[row * LPITCH + c4 * 4] = src[m];
  }
  __syncthreads();
  const bool right = s >= HALF;
  const int step = right ? (SITES - 1 - s) : s;
  float4* out = (float4*)(P + (right ? PR_OFF : 0) + (size_t)step * SITE_FLOATS);
  #pragma unroll
  for (int k = 0; k < 8; ++k) {
    const int m2 = t + 256 * k;
    const int j  = m2 & 63;
    const int fq = m2 >> 6;
    const int f  = fq >> 4;
    const int q  = fq & 15;
    float4 v;
    if (!right) {
      v.x = ld[(4 * q + 0) * LPITCH + 2 * j + f];
      v.y = ld[(4 * q + 1) * LPITCH + 2 * j + f];
      v.z = ld[(4 * q + 2) * LPITCH + 2 * j + f];
      v.w = ld[(4 * q + 3) * LPITCH + 2 * j + f];
    } else {
      v.x = ld[j * LPITCH + 2 * (4 * q + 0) + f];
      v.y = ld[j * LPITCH + 2 * (4 * q + 1) + f];
      v.z = ld[j * LPITCH + 2 * (4 * q + 2) + f];
      v.w = ld[j * LPITCH + 2 * (4 * q + 3) + f];
    }
    out[m2] = v;
  }
}

// ---------------------------------------------------------------------------
// Chain: 256 blocks x 128 threads (wave 0 = consumer/compute, wave 1 =
// producer/staging). Producer streams sites into a 3-deep LDS ring via
// global_load_lds, gating with manual s_waitcnt vmcnt(32); consumer never
// issues vector-memory in its loop, so its vmcnt is always satisfied and its
// ds_read_b128->FMA stream gets the compiler's precise lgkm pipelining.
// Sync: monotone LDS flags (relaxed atomics), no barriers in the loop.
// Ends with a fused per-batch combine: the later of a batch's two blocks
// (agent-scope atomic) computes logits[b][0..9].
// ---------------------------------------------------------------------------
__global__ void __launch_bounds__(128, 1)
mps_chain_kernel(const float* __restrict__ input,   // [128][256][2]
                 const float* __restrict__ P,       // packed cores (in ws)
                 const float* __restrict__ lvec,
                 const float* __restrict__ rvec,
                 const float* __restrict__ oc,      // [10][64][64]
                 float* __restrict__ vout,          // ws + VEC_OFF
                 int* __restrict__ cnt,             // ws + CNT_OFF
                 float* __restrict__ out) {         // [128][10]
  __shared__ __align__(16) float buf0[SITE_FLOATS];
  __shared__ __align__(16) float buf1[SITE_FLOATS];
  __shared__ __align__(16) float buf2[SITE_FLOATS];
  __shared__ __align__(16) float xsh[HALF * 2];
  __shared__ int flags[2];                  // [0]=ready (steps staged), [1]=done
  __shared__ int finisher;

  const int t    = (int)threadIdx.x;
  const int w    = t >> 6;
  const int lane = t & 63;
  const int bid  = (int)blockIdx.x;
  // XCD pinning (XCD = bid % 8): XCDs 0-3 -> side 0, XCDs 4-7 -> side 1.
  const int side = ((bid & 7) < 4) ? 0 : 1;
  const int b    = (bid >> 3) * 4 + (bid & 3);   // 0..127, unique per side

  if (t == 0) { flags[0] = -1; flags[1] = -1; }
  if (w == 0)
    ((float4*)xsh)[lane] =
        ((const float4*)(input + (size_t)b * SITES * 2 + side * HALF * 2))[lane];
  __syncthreads();

  const float* base = P + (side ? PR_OFF : 0);

  if (w == 1) {
    // ---------------- producer ----------------
    for (int s = 0; s < HALF; ++s) {
      if (s >= 3)
        while (__hip_atomic_load(&flags[1], __ATOMIC_RELAXED,
                                 __HIP_MEMORY_SCOPE_WORKGROUP) < s - 3) {}
      float* nb = (s % 3 == 0) ? buf0 : ((s % 3 == 1) ? buf1 : buf2);
      const float* g = base + (size_t)s * SITE_FLOATS;
      #pragma unroll
      for (int c = 0; c < 32; ++c)
        gload_lds16(g + c * 256 + lane * 4, nb + c * 256);
      // all steps older than s have landed once <=32 remain outstanding
      asm volatile("s_waitcnt vmcnt(32)" ::: "memory");
      __hip_atomic_store(&flags[0], s - 1, __ATOMIC_RELAXED,
                         __HIP_MEMORY_SCOPE_WORKGROUP);
    }
    asm volatile("s_waitcnt vmcnt(0)" ::: "memory");
    __hip_atomic_store(&flags[0], HALF - 1, __ATOMIC_RELAXED,
                       __HIP_MEMORY_SCOPE_WORKGROUP);
  } else {
    // ---------------- consumer / compute ----------------
    float vcur = side ? rvec[lane] : lvec[lane];
    for (int i = 0; i < HALF; ++i) {
      // broadcast v into wave-uniform values (VALU only, buffer-independent)
      float sv[BOND];
      #pragma unroll
      for (int l = 0; l < BOND; ++l)
        sv[l] = __int_as_float(
            __builtin_amdgcn_readlane(__float_as_int(vcur), l));
      while (__hip_atomic_load(&flags[0], __ATOMIC_RELAXED,
                               __HIP_MEMORY_SCOPE_WORKGROUP) < i) {}
      const float* B = (i % 3 == 0) ? buf0 : ((i % 3 == 1) ? buf1 : buf2);
      float a0 = 0.f, a1 = 0.f, c0 = 0.f, c1 = 0.f;
      #pragma unroll
      for (int q = 0; q < 16; ++q) {
        const float4 m0 = ((const float4*)(B + q * 256))[lane];        // f=0
        const float4 m1 = ((const float4*)(B + 4096 + q * 256))[lane]; // f=1
        a0 = __builtin_fmaf(sv[4 * q + 0], m0.x, a0);
        a1 = __builtin_fmaf(sv[4 * q + 1], m0.y, a1);
        a0 = __builtin_fmaf(sv[4 * q + 2], m0.z, a0);
        a1 = __builtin_fmaf(sv[4 * q + 3], m0.w, a1);
        c0 = __builtin_fmaf(sv[4 * q + 0], m1.x, c0);
        c1 = __builtin_fmaf(sv[4 * q + 1], m1.y, c1);
        c0 = __builtin_fmaf(sv[4 * q + 2], m1.z, c0);
        c1 = __builtin_fmaf(sv[4 * q + 3], m1.w, c1);
      }
      const int xi = side ? (HALF - 1 - i) : i;
      const float2 xx = ((const float2*)xsh)[xi];
      vcur = __builtin_fmaf(xx.x, a0 + a1, __builtin_fmaf(xx.y, c0 + c1, vcur));
      // order the done-publish after this step's consumption
      asm volatile("" :: "v"(vcur));
      __hip_atomic_store(&flags[1], i, __ATOMIC_RELAXED,
                         __HIP_MEMORY_SCOPE_WORKGROUP);
    }
    vout[((size_t)side * NBATCH + b) * BOND + lane] = vcur;
  }

  // ---------------- fused combine (last finisher of batch b) ----------------
  __threadfence();                 // make vout visible device-wide
  __syncthreads();
  if (t == 0)
    finisher = __hip_atomic_fetch_add(&cnt[b], 1, __ATOMIC_ACQ_REL,
                                      __HIP_MEMORY_SCOPE_AGENT);
  __syncthreads();
  if (finisher == 1) {
    const float* vl = vout + (size_t)b * BOND;                 // left result
    const float vrr = vout[(size_t)NBATCH * BOND + b * BOND + lane];
    #pragma unroll
    for (int oo = 0; oo < 5; ++oo) {
      const int o = w * 5 + oo;
      float acc = 0.f;
      #pragma unroll
      for (int m = 0; m < BOND; ++m)
        acc = __builtin_fmaf(vl[m], oc[(o * BOND + m) * BOND + lane], acc);
      acc *= vrr;
      #pragma unroll
      for (int off = 32; off > 0; off >>= 1)
        acc += __shfl_xor(acc, off, 64);
      if (lane == 0) out[b * OUTD + o] = acc;
    }
  }
}

extern "C" void kernel_launch(void* const* d_in, const int* in_sizes, int n_in,
                              void* d_out, int out_size, void* d_ws, size_t ws_size,
                              hipStream_t stream) {
  const float* input = (const float*)d_in[0];   // [128][256][2]
  const float* cores = (const float*)d_in[1];   // [256][64][64][2]
  const float* oc    = (const float*)d_in[2];   // [10][64][64]
  const float* lvec  = (const float*)d_in[3];   // [64]
  const float* rvec  = (const float*)d_in[4];   // [64]
  float* ws  = (float*)d_ws;
  int*   cnt = (int*)(ws + CNT_OFF);
  float* out = (float*)d_out;                   // [128][10]

  hipLaunchKernelGGL(mps_pack_kernel, dim3(SITES), dim3(256), 0, stream,
                     cores, ws, cnt);
  hipLaunchKernelGGL(mps_chain_kernel, dim3(2 * NBATCH), dim3(128), 0, stream,
                     input, ws, lvec, rvec, oc, ws + VEC_OFF, cnt, out);
}